// Round 6
// baseline (295.022 us; speedup 1.0000x reference)
//
#include <hip/hip_runtime.h>
#include <math.h>

#define BATCH 1024
#define DIM   256
#define NCL   50000
#define TOTC  100000   // 2*NC
#define NSLICE 16

typedef __attribute__((ext_vector_type(8)))  short bf16x8;   // 8 bf16 = 4 VGPR
typedef __attribute__((ext_vector_type(16))) float f32x16;   // 32x32 acc frag

typedef const __attribute__((address_space(1))) unsigned int* gas_u32p;
typedef __attribute__((address_space(3))) unsigned int* las_u32p;

__device__ __forceinline__ unsigned short f2bf(float f) {   // RNE f32 -> bf16
    unsigned int u = __float_as_uint(f);
    return (unsigned short)((u + 0x7FFFu + ((u >> 16) & 1u)) >> 16);
}

// ---------------------------------------------------------------------------
// Kernel 1: normalize rows -> bf16 xn written PRE-SWIZZLED (16B-chunk index
// XOR (row&31)) so k_main stages it with a linear global_load_lds copy and
// reads fragments conflict-free; target logits (f32); zero sliced accums.
// ---------------------------------------------------------------------------
__global__ __launch_bounds__(64) void k_prep(const float* __restrict__ in,
                                             const int* __restrict__ tgt,
                                             const float* __restrict__ feats,
                                             unsigned short* __restrict__ xnb,
                                             float* __restrict__ Sx,
                                             float* __restrict__ z) {
    const int b = blockIdx.x;
    const int t = threadIdx.x;           // 0..63, 4 floats each
    float4 v = *(const float4*)&in[b * DIM + t * 4];
    float ss = v.x * v.x + v.y * v.y + v.z * v.z + v.w * v.w;
#pragma unroll
    for (int o = 1; o < 64; o <<= 1) ss += __shfl_xor(ss, o, 64);
    const float sc = 1.0f / sqrtf(ss);
    float4 w;
    w.x = v.x * sc; w.y = v.y * sc; w.z = v.z * sc; w.w = v.w * sc;

    // swizzled write: thread t owns 8 bytes at logical chunk (t>>1), half (t&1)
    const int cd = (t >> 1) ^ (b & 31);
    uint2 p;
    p.x = (unsigned int)f2bf(w.x) | ((unsigned int)f2bf(w.y) << 16);
    p.y = (unsigned int)f2bf(w.z) | ((unsigned int)f2bf(w.w) << 16);
    *(uint2*)((char*)xnb + b * 512 + (cd << 4) + (t & 1) * 8) = p;

    const int tb = tgt[b];
#pragma unroll
    for (int h = 0; h < 2; ++h) {
        const int row = tb + h * NCL;    // mean half rows [0,NC), hard [NC,2NC)
        float4 f = *(const float4*)&feats[row * DIM + t * 4];
        float d = w.x * f.x + w.y * f.y + w.z * f.z + w.w * f.w;
#pragma unroll
        for (int o = 1; o < 64; o <<= 1) d += __shfl_xor(d, o, 64);
        if (t == 0) z[b * 2 + h] = d * 20.0f;
    }
    // zero sliced accumulators: 16*1024*2 = 32768 floats over 1024 blocks
    if (t < 32) Sx[b * 32 + t] = 0.0f;
}

// ---------------------------------------------------------------------------
// Kernel 2: MFMA GEMM + fused sumexp.
// 391 blocks x 8 waves (4M x 2N); block owns 256 clusters. Wave caches its
// 64 cluster rows as A-frags in 128 VGPRs (chunked load->convert for deep
// VMEM pipelining). Batch staged in 64-row tiles (32 KB), double-buffered
// (64 KB LDS -> 2 blocks/CU co-resident). Counted vmcnt(4) + raw barriers;
// NO atomics inside the loop — per-bt sums go to statically-indexed sregs,
// atomics fire once at kernel end.
// ---------------------------------------------------------------------------
__global__ __launch_bounds__(512, 4) void k_main(const unsigned short* __restrict__ xnb,
                                                 const float* __restrict__ feats,
                                                 float* __restrict__ Sx) {
    __shared__ unsigned short Bb[2][64 * 256];   // 2 x 32 KB double buffer

    const int tid  = threadIdx.x;
    const int lane = tid & 63;
    const int wid  = tid >> 6;        // 0..7
    const int wm   = wid >> 1;        // 0..3  (M offset wm*64)
    const int wn   = wid & 1;         // 0..1  (N offset wn*32)
    const int l31  = lane & 31;
    const int hi   = lane >> 5;       // 0/1
    const int cb0  = blockIdx.x * 256;
    float* Ss = Sx + (blockIdx.x & (NSLICE - 1)) * (BATCH * 2);

#define STAGE(bufp, bt_) do {                                              \
        const char* sb_ = (const char*)xnb + (size_t)(bt_) * 32768;        \
        _Pragma("unroll")                                                  \
        for (int i_ = 0; i_ < 4; ++i_) {                                   \
            const int off_ = wid * 4096 + i_ * 1024;                       \
            __builtin_amdgcn_global_load_lds(                              \
                (gas_u32p)(sb_ + off_ + lane * 16),                        \
                (las_u32p)((char*)(bufp) + off_), 16, 0, 0);               \
        }                                                                  \
    } while (0)

    // ---- issue tile-0 staging first: it streams in under the A-phase ----
    STAGE(Bb[0], 0);

    // ---- A cache: 2 M-frags x 16 K-steps; lane holds row (base+l31),
    //      k = kk*16 + hi*8 + j. Chunked: 8 load-pairs in flight, then
    //      convert — keeps the VMEM queue deep without 256 live f32 regs.
    bf16x8 ac[2][16];
#pragma unroll
    for (int mt = 0; mt < 2; ++mt) {
        int row = cb0 + wm * 64 + mt * 32 + l31;
        if (row > TOTC - 1) row = TOTC - 1;        // clamp; masked in epilogue
        const float* rp = &feats[(size_t)row * DIM];
#pragma unroll
        for (int ch = 0; ch < 2; ++ch) {
            float4 t0[8], t1[8];
#pragma unroll
            for (int q = 0; q < 8; ++q) {
                const int kk = ch * 8 + q;
                t0[q] = *(const float4*)&rp[kk * 16 + hi * 8];
                t1[q] = *(const float4*)&rp[kk * 16 + hi * 8 + 4];
            }
#pragma unroll
            for (int q = 0; q < 8; ++q) {
                const int kk = ch * 8 + q;
                bf16x8 a;
                a[0] = (short)f2bf(t0[q].x); a[1] = (short)f2bf(t0[q].y);
                a[2] = (short)f2bf(t0[q].z); a[3] = (short)f2bf(t0[q].w);
                a[4] = (short)f2bf(t1[q].x); a[5] = (short)f2bf(t1[q].y);
                a[6] = (short)f2bf(t1[q].z); a[7] = (short)f2bf(t1[q].w);
                ac[mt][kk] = a;
            }
        }
    }

    const bool mixed = (cb0 < NCL && cb0 + 255 >= NCL) || (cb0 + 255 >= TOTC);
    const int  halfsel = (cb0 >= NCL) ? 1 : 0;

    float sreg0[16], sreg1[16];

#pragma unroll
    for (int bt = 0; bt < 16; ++bt) {
        const int cur = bt & 1;
        if (bt < 15) {
            STAGE(Bb[cur ^ 1], bt + 1);
            // drain everything older than the 4 just-issued loads
            asm volatile("s_waitcnt vmcnt(4)" ::: "memory");
        } else {
            asm volatile("s_waitcnt vmcnt(0)" ::: "memory");
        }
        __builtin_amdgcn_sched_barrier(0);
        __builtin_amdgcn_s_barrier();       // stage(bt) visible to all waves
        __builtin_amdgcn_sched_barrier(0);

        // ---- compute: K = 256 in 16 steps; 1 ds_read_b128 + 2 MFMA/step ----
        f32x16 acc0 = (f32x16)(0.0f), acc1 = (f32x16)(0.0f);
        const char* bb = (const char*)Bb[cur];
#pragma unroll
        for (int kk = 0; kk < 16; ++kk) {
            const int kc = (kk * 2 + hi) ^ l31;           // swizzled 16B chunk
            const bf16x8 bf = *(const bf16x8*)(bb + (wn * 32 + l31) * 512 + (kc << 4));
            acc0 = __builtin_amdgcn_mfma_f32_32x32x16_bf16(ac[0][kk], bf, acc0, 0, 0, 0);
            acc1 = __builtin_amdgcn_mfma_f32_32x32x16_bf16(ac[1][kk], bf, acc1, 0, 0, 0);
        }
        __builtin_amdgcn_sched_barrier(0);
        __builtin_amdgcn_s_barrier();       // all reads of Bb[cur] done before
        __builtin_amdgcn_sched_barrier(0);  // next iter's stage overwrites it

        // ---- epilogue (register-only, floats past the barrier) ----
        if (!mixed) {
            float s = 0.0f;
#pragma unroll
            for (int r = 0; r < 16; ++r) {
                s += __expf(fmaf(acc0[r], 20.0f, -20.0f));
                s += __expf(fmaf(acc1[r], 20.0f, -20.0f));
            }
            s += __shfl_xor(s, 32, 64);
            sreg0[bt] = s;
            sreg1[bt] = 0.0f;
        } else {
            float sh0 = 0.0f, sh1 = 0.0f;
#pragma unroll
            for (int mt = 0; mt < 2; ++mt)
#pragma unroll
                for (int r = 0; r < 16; ++r) {
                    const int cl = cb0 + wm * 64 + mt * 32 +
                                   (r & 3) + 8 * (r >> 2) + 4 * hi;
                    const bool valid = cl < TOTC;
                    float e = __expf(fmaf((mt ? acc1[r] : acc0[r]), 20.0f, -20.0f));
                    e = valid ? e : 0.0f;
                    sh0 += (cl < NCL) ? e : 0.0f;
                    sh1 += (cl < NCL) ? 0.0f : e;
                }
            sh0 += __shfl_xor(sh0, 32, 64);
            sh1 += __shfl_xor(sh1, 32, 64);
            sreg0[bt] = sh0;
            sreg1[bt] = sh1;
        }
    }

    // ---- all atomics at the very end: fire-and-forget ----
    if (hi == 0) {
        if (!mixed) {
#pragma unroll
            for (int bt = 0; bt < 16; ++bt) {
                const int bcol = bt * 64 + wn * 32 + l31;
                atomicAdd(&Ss[bcol * 2 + halfsel], sreg0[bt]);
            }
        } else {
#pragma unroll
            for (int bt = 0; bt < 16; ++bt) {
                const int bcol = bt * 64 + wn * 32 + l31;
                atomicAdd(&Ss[bcol * 2 + 0], sreg0[bt]);
                atomicAdd(&Ss[bcol * 2 + 1], sreg1[bt]);
            }
        }
    }
#undef STAGE
}

// ---------------------------------------------------------------------------
// Kernel 3: loss = 0.5 * mean_b[(20+log S0 - z0) + (20+log S1 - z1)],
// summing the 16 slices first.
// ---------------------------------------------------------------------------
__global__ __launch_bounds__(256) void k_loss(const float* __restrict__ Sx,
                                              const float* __restrict__ z,
                                              float* __restrict__ out) {
    const int t = threadIdx.x;
    float part = 0.0f;
    for (int r = t; r < BATCH; r += 256) {
        float s0 = 0.0f, s1 = 0.0f;
#pragma unroll
        for (int sl = 0; sl < NSLICE; ++sl) {
            s0 += Sx[sl * (BATCH * 2) + r * 2 + 0];
            s1 += Sx[sl * (BATCH * 2) + r * 2 + 1];
        }
        part += 40.0f + logf(s0) + logf(s1) - z[r * 2 + 0] - z[r * 2 + 1];
    }
#pragma unroll
    for (int o = 1; o < 64; o <<= 1) part += __shfl_xor(part, o, 64);
    __shared__ float ws[4];
    if ((t & 63) == 0) ws[t >> 6] = part;
    __syncthreads();
    if (t == 0) {
        const float tot = ws[0] + ws[1] + ws[2] + ws[3];
        out[0] = 0.5f * tot / (float)BATCH;
    }
}

// ---------------------------------------------------------------------------
extern "C" void kernel_launch(void* const* d_in, const int* in_sizes, int n_in,
                              void* d_out, int out_size, void* d_ws, size_t ws_size,
                              hipStream_t stream) {
    const float* inputs  = (const float*)d_in[0];
    const int*   targets = (const int*)d_in[1];
    const float* feats   = (const float*)d_in[2];
    float* out = (float*)d_out;

    unsigned short* xnb = (unsigned short*)d_ws;          // 1024*256 bf16 = 512 KB
    float* Sx = (float*)(xnb + BATCH * DIM);              // 16*1024*2 f32 = 128 KB
    float* zt = Sx + NSLICE * BATCH * 2;                  // 1024*2 f32

    k_prep<<<BATCH, 64, 0, stream>>>(inputs, targets, feats, xnb, Sx, zt);
    const int nblk = (TOTC + 255) / 256;                  // 391
    k_main<<<nblk, 512, 0, stream>>>(xnb, feats, Sx);
    k_loss<<<1, 256, 0, stream>>>(Sx, zt, out);
}

// Round 7
// 155.393 us; speedup vs baseline: 1.8986x; 1.8986x over previous
//
#include <hip/hip_runtime.h>
#include <math.h>

#define BATCH 1024
#define DIM   256
#define NCL   50000
#define TOTC  100000   // 2*NC
#define NSLICE 16

typedef __attribute__((ext_vector_type(8)))  short bf16x8;   // 8 bf16 = 4 VGPR
typedef __attribute__((ext_vector_type(16))) float f32x16;   // 32x32 acc frag

__device__ __forceinline__ unsigned short f2bf(float f) {   // RNE f32 -> bf16
    unsigned int u = __float_as_uint(f);
    return (unsigned short)((u + 0x7FFFu + ((u >> 16) & 1u)) >> 16);
}

// ---------------------------------------------------------------------------
// Kernel 1: normalize rows -> bf16 xn stored TRANSPOSED in k-panels:
// element (k, b) lives at panel p=k>>3, address p*16384 + b*16 + (k&7)*2.
// A 32x32x16-MFMA B-fragment (col=lane&31, k=kk*16+hi*8..+7) is then ONE
// 16B load, coalesced across lanes (512B runs). Also: target logits, zero
// sliced accumulators. One wave per batch row.
// ---------------------------------------------------------------------------
__global__ __launch_bounds__(64) void k_prep(const float* __restrict__ in,
                                             const int* __restrict__ tgt,
                                             const float* __restrict__ feats,
                                             unsigned short* __restrict__ xnT,
                                             float* __restrict__ Sx,
                                             float* __restrict__ z) {
    const int b = blockIdx.x;
    const int t = threadIdx.x;           // 0..63, 4 floats each (k = t*4..t*4+3)
    float4 v = *(const float4*)&in[b * DIM + t * 4];
    float ss = v.x * v.x + v.y * v.y + v.z * v.z + v.w * v.w;
#pragma unroll
    for (int o = 1; o < 64; o <<= 1) ss += __shfl_xor(ss, o, 64);
    const float sc = 1.0f / sqrtf(ss);
    float4 w;
    w.x = v.x * sc; w.y = v.y * sc; w.z = v.z * sc; w.w = v.w * sc;

    // panel write: panel = t>>1, within-row byte offset (t&1)*8
    uint2 p;
    p.x = (unsigned int)f2bf(w.x) | ((unsigned int)f2bf(w.y) << 16);
    p.y = (unsigned int)f2bf(w.z) | ((unsigned int)f2bf(w.w) << 16);
    *(uint2*)((char*)xnT + (t >> 1) * 16384 + b * 16 + (t & 1) * 8) = p;

    const int tb = tgt[b];
#pragma unroll
    for (int h = 0; h < 2; ++h) {
        const int row = tb + h * NCL;    // mean half rows [0,NC), hard [NC,2NC)
        float4 f = *(const float4*)&feats[row * DIM + t * 4];
        float d = w.x * f.x + w.y * f.y + w.z * f.z + w.w * f.w;
#pragma unroll
        for (int o = 1; o < 64; o <<= 1) d += __shfl_xor(d, o, 64);
        if (t == 0) z[b * 2 + h] = d * 20.0f;
    }
    // zero sliced accumulators: 16*1024*2 = 32768 floats over 1024 blocks
    if (t < 32) Sx[b * 32 + t] = 0.0f;
}

// ---------------------------------------------------------------------------
// Kernel 2: MFMA GEMM + fused sumexp. NO LDS, NO barriers, NO vmcnt
// choreography, NO in-loop atomics — every wave free-runs.
// 782 blocks x 8 waves (2M x 4N); block owns 128 clusters. Wave caches its
// 64 cluster rows as A-frags in 128 VGPRs (chunked load->convert). B-frags
// come straight from the L2-resident transposed xnT, one coalesced 16B
// load each. Per-bt sums -> statically-indexed sregs; atomics fire once at
// kernel end (fire-and-forget, nothing ever waits on them).
// ---------------------------------------------------------------------------
__global__ __launch_bounds__(512) void k_main(const unsigned short* __restrict__ xnT,
                                              const float* __restrict__ feats,
                                              float* __restrict__ Sx) {
    const int tid  = threadIdx.x;
    const int lane = tid & 63;
    const int wid  = tid >> 6;        // 0..7
    const int wm   = wid >> 2;        // 0..1  (M offset wm*64)
    const int wn   = wid & 3;         // 0..3  (N offset wn*32)
    const int l31  = lane & 31;
    const int hi   = lane >> 5;       // 0/1
    const int cb0  = blockIdx.x * 128;
    float* Ss = Sx + (blockIdx.x & (NSLICE - 1)) * (BATCH * 2);

    // ---- A cache: 2 M-frags x 16 K-steps; lane holds row (base+l31),
    //      k = kk*16 + hi*8 + j. Chunked: 8 load-pairs in flight, then
    //      convert — deep VMEM pipeline without 256 live f32 regs. ----
    bf16x8 ac[2][16];
#pragma unroll
    for (int mt = 0; mt < 2; ++mt) {
        int row = cb0 + wm * 64 + mt * 32 + l31;
        if (row > TOTC - 1) row = TOTC - 1;        // clamp; masked in epilogue
        const float* rp = &feats[(size_t)row * DIM];
#pragma unroll
        for (int ch = 0; ch < 2; ++ch) {
            float4 t0[8], t1[8];
#pragma unroll
            for (int q = 0; q < 8; ++q) {
                const int kk = ch * 8 + q;
                t0[q] = *(const float4*)&rp[kk * 16 + hi * 8];
                t1[q] = *(const float4*)&rp[kk * 16 + hi * 8 + 4];
            }
#pragma unroll
            for (int q = 0; q < 8; ++q) {
                const int kk = ch * 8 + q;
                bf16x8 a;
                a[0] = (short)f2bf(t0[q].x); a[1] = (short)f2bf(t0[q].y);
                a[2] = (short)f2bf(t0[q].z); a[3] = (short)f2bf(t0[q].w);
                a[4] = (short)f2bf(t1[q].x); a[5] = (short)f2bf(t1[q].y);
                a[6] = (short)f2bf(t1[q].z); a[7] = (short)f2bf(t1[q].w);
                ac[mt][kk] = a;
            }
        }
    }

    const bool mixed = (cb0 < NCL && cb0 + 127 >= NCL) || (cb0 + 127 >= TOTC);
    const int  halfsel = (cb0 >= NCL) ? 1 : 0;

    float sreg0[8], sreg1[8];

#pragma unroll
    for (int bt = 0; bt < 8; ++bt) {
        // B base for this wave: batch col bt*128 + wn*32 + l31, panel hi
        const unsigned short* bb = xnT + (size_t)hi * (BATCH * 8)
                                 + (size_t)(bt * 128 + wn * 32 + l31) * 8;

        f32x16 acc0 = (f32x16)(0.0f), acc1 = (f32x16)(0.0f);
#pragma unroll
        for (int kk = 0; kk < 16; ++kk) {
            // panel stride: 2 panels per kk = 16384 ushorts
            const bf16x8 bf = *(const bf16x8*)(bb + (size_t)kk * 16384);
            acc0 = __builtin_amdgcn_mfma_f32_32x32x16_bf16(ac[0][kk], bf, acc0, 0, 0, 0);
            acc1 = __builtin_amdgcn_mfma_f32_32x32x16_bf16(ac[1][kk], bf, acc1, 0, 0, 0);
        }

        // ---- epilogue: e = exp(20*d - 20); sum over this wave's 64 clusters
        if (!mixed) {
            float s = 0.0f;
#pragma unroll
            for (int r = 0; r < 16; ++r) {
                s += __expf(fmaf(acc0[r], 20.0f, -20.0f));
                s += __expf(fmaf(acc1[r], 20.0f, -20.0f));
            }
            s += __shfl_xor(s, 32, 64);
            sreg0[bt] = s;
            sreg1[bt] = 0.0f;
        } else {
            float sh0 = 0.0f, sh1 = 0.0f;
#pragma unroll
            for (int mt = 0; mt < 2; ++mt)
#pragma unroll
                for (int r = 0; r < 16; ++r) {
                    const int cl = cb0 + wm * 64 + mt * 32 +
                                   (r & 3) + 8 * (r >> 2) + 4 * hi;
                    const bool valid = cl < TOTC;
                    float e = __expf(fmaf((mt ? acc1[r] : acc0[r]), 20.0f, -20.0f));
                    e = valid ? e : 0.0f;
                    sh0 += (cl < NCL) ? e : 0.0f;
                    sh1 += (cl < NCL) ? 0.0f : e;
                }
            sh0 += __shfl_xor(sh0, 32, 64);
            sh1 += __shfl_xor(sh1, 32, 64);
            sreg0[bt] = sh0;
            sreg1[bt] = sh1;
        }
    }

    // ---- all atomics at the very end: fire-and-forget ----
    if (hi == 0) {
        if (!mixed) {
#pragma unroll
            for (int bt = 0; bt < 8; ++bt) {
                const int bcol = bt * 128 + wn * 32 + l31;
                atomicAdd(&Ss[bcol * 2 + halfsel], sreg0[bt]);
            }
        } else {
#pragma unroll
            for (int bt = 0; bt < 8; ++bt) {
                const int bcol = bt * 128 + wn * 32 + l31;
                atomicAdd(&Ss[bcol * 2 + 0], sreg0[bt]);
                atomicAdd(&Ss[bcol * 2 + 1], sreg1[bt]);
            }
        }
    }
}

// ---------------------------------------------------------------------------
// Kernel 3: loss = 0.5 * mean_b[(20+log S0 - z0) + (20+log S1 - z1)],
// summing the 16 slices first.
// ---------------------------------------------------------------------------
__global__ __launch_bounds__(256) void k_loss(const float* __restrict__ Sx,
                                              const float* __restrict__ z,
                                              float* __restrict__ out) {
    const int t = threadIdx.x;
    float part = 0.0f;
    for (int r = t; r < BATCH; r += 256) {
        float s0 = 0.0f, s1 = 0.0f;
#pragma unroll
        for (int sl = 0; sl < NSLICE; ++sl) {
            s0 += Sx[sl * (BATCH * 2) + r * 2 + 0];
            s1 += Sx[sl * (BATCH * 2) + r * 2 + 1];
        }
        part += 40.0f + logf(s0) + logf(s1) - z[r * 2 + 0] - z[r * 2 + 1];
    }
#pragma unroll
    for (int o = 1; o < 64; o <<= 1) part += __shfl_xor(part, o, 64);
    __shared__ float ws[4];
    if ((t & 63) == 0) ws[t >> 6] = part;
    __syncthreads();
    if (t == 0) {
        const float tot = ws[0] + ws[1] + ws[2] + ws[3];
        out[0] = 0.5f * tot / (float)BATCH;
    }
}

// ---------------------------------------------------------------------------
extern "C" void kernel_launch(void* const* d_in, const int* in_sizes, int n_in,
                              void* d_out, int out_size, void* d_ws, size_t ws_size,
                              hipStream_t stream) {
    const float* inputs  = (const float*)d_in[0];
    const int*   targets = (const int*)d_in[1];
    const float* feats   = (const float*)d_in[2];
    float* out = (float*)d_out;

    unsigned short* xnT = (unsigned short*)d_ws;          // 32 panels * 16 KB = 512 KB
    float* Sx = (float*)(xnT + BATCH * DIM);              // 16*1024*2 f32 = 128 KB
    float* zt = Sx + NSLICE * BATCH * 2;                  // 1024*2 f32

    k_prep<<<BATCH, 64, 0, stream>>>(inputs, targets, feats, xnT, Sx, zt);
    const int nblk = (TOTC + 127) / 128;                  // 782
    k_main<<<nblk, 512, 0, stream>>>(xnT, feats, Sx);
    k_loss<<<1, 256, 0, stream>>>(Sx, zt, out);
}

// Round 8
// 92.151 us; speedup vs baseline: 3.2015x; 1.6863x over previous
//
#include <hip/hip_runtime.h>
#include <math.h>

#define BATCH 1024
#define DIM   256
#define NCL   50000
#define TOTC  100000   // 2*NC
#define NSLICE 16

typedef __attribute__((ext_vector_type(8)))  short bf16x8;   // 8 bf16 = 4 VGPR
typedef __attribute__((ext_vector_type(16))) float f32x16;   // 32x32 acc frag

__device__ __forceinline__ unsigned short f2bf(float f) {   // RNE f32 -> bf16
    unsigned int u = __float_as_uint(f);
    return (unsigned short)((u + 0x7FFFu + ((u >> 16) & 1u)) >> 16);
}

// ---------------------------------------------------------------------------
// Kernel 1: normalize rows -> bf16 xn stored TRANSPOSED in k-panels:
// element (k, b) lives at panel p=k>>3, address p*16384 + b*16 + (k&7)*2.
// A 32x32x16-MFMA B-fragment (col=lane&31, k=kk*16+hi*8..+7) is then ONE
// coalesced 16B load (512B runs across lanes). Also: target logits, zero
// sliced accumulators. One wave per batch row.
// ---------------------------------------------------------------------------
__global__ __launch_bounds__(64) void k_prep(const float* __restrict__ in,
                                             const int* __restrict__ tgt,
                                             const float* __restrict__ feats,
                                             unsigned short* __restrict__ xnT,
                                             float* __restrict__ Sx,
                                             float* __restrict__ z) {
    const int b = blockIdx.x;
    const int t = threadIdx.x;           // 0..63, 4 floats each (k = t*4..t*4+3)
    float4 v = *(const float4*)&in[b * DIM + t * 4];
    float ss = v.x * v.x + v.y * v.y + v.z * v.z + v.w * v.w;
#pragma unroll
    for (int o = 1; o < 64; o <<= 1) ss += __shfl_xor(ss, o, 64);
    const float sc = 1.0f / sqrtf(ss);
    float4 w;
    w.x = v.x * sc; w.y = v.y * sc; w.z = v.z * sc; w.w = v.w * sc;

    // panel write: panel = t>>1, within-row byte offset (t&1)*8
    uint2 p;
    p.x = (unsigned int)f2bf(w.x) | ((unsigned int)f2bf(w.y) << 16);
    p.y = (unsigned int)f2bf(w.z) | ((unsigned int)f2bf(w.w) << 16);
    *(uint2*)((char*)xnT + (t >> 1) * 16384 + b * 16 + (t & 1) * 8) = p;

    const int tb = tgt[b];
#pragma unroll
    for (int h = 0; h < 2; ++h) {
        const int row = tb + h * NCL;    // mean half rows [0,NC), hard [NC,2NC)
        float4 f = *(const float4*)&feats[row * DIM + t * 4];
        float d = w.x * f.x + w.y * f.y + w.z * f.z + w.w * f.w;
#pragma unroll
        for (int o = 1; o < 64; o <<= 1) d += __shfl_xor(d, o, 64);
        if (t == 0) z[b * 2 + h] = d * 20.0f;
    }
    // zero sliced accumulators: 16*1024*2 = 32768 floats over 1024 blocks
    if (t < 32) Sx[b * 32 + t] = 0.0f;
}

// ---------------------------------------------------------------------------
// Kernel 2: MFMA GEMM + fused sumexp.
// 782 blocks x 8 waves (2M x 4N); block owns 128 clusters. A (feature rows,
// f32->bf16) is staged ONCE into 64 KB LDS (XOR-swizzled), ONE barrier,
// then the main loop is barrier-free: per kk, 2 ds_read_b128 (A) +
// 1 coalesced 16B global load (B from transposed xnT, L2-resident) +
// 2 MFMA. Registers stay free (~100 VGPRs) so the compiler pipelines
// loads deep; LDS 64KB -> 2 blocks/CU -> 4 waves/SIMD TLP on top.
// Per-bt sums -> statically-indexed sregs; atomics once at kernel end.
// ---------------------------------------------------------------------------
__global__ __launch_bounds__(512) void k_main(const unsigned short* __restrict__ xnT,
                                              const float* __restrict__ feats,
                                              float* __restrict__ Sx) {
    __shared__ unsigned short Ab[128 * 256];   // 64 KB, block-lifetime constant

    const int tid  = threadIdx.x;
    const int lane = tid & 63;
    const int wid  = tid >> 6;        // 0..7
    const int wm   = wid >> 2;        // 0..1  (M offset wm*64)
    const int wn   = wid & 3;         // 0..3  (N offset wn*32)
    const int l31  = lane & 31;
    const int hi   = lane >> 5;       // 0/1
    const int cb0  = blockIdx.x * 128;
    float* Ss = Sx + (blockIdx.x & (NSLICE - 1)) * (BATCH * 2);

    // ---- stage A: 128 rows x 256 f32 -> bf16, swizzled; coalesced reads ----
#pragma unroll
    for (int it = 0; it < 16; ++it) {
        const int f  = it * 512 + tid;       // float4 index, 8192 total
        const int r  = f >> 6;               // 0..127 (64 float4 per row)
        const int c4 = f & 63;
        int gr = cb0 + r;
        if (gr > TOTC - 1) gr = TOTC - 1;    // clamp; masked in epilogue
        const float4 v = *(const float4*)&feats[(size_t)gr * DIM + c4 * 4];
        uint2 p;
        p.x = (unsigned int)f2bf(v.x) | ((unsigned int)f2bf(v.y) << 16);
        p.y = (unsigned int)f2bf(v.z) | ((unsigned int)f2bf(v.w) << 16);
        const int byte = r * 512 + (((c4 >> 1) * 16) ^ ((r & 7) << 4)) + (c4 & 1) * 8;
        *(uint2*)((char*)Ab + byte) = p;
    }
    __syncthreads();                         // the ONLY barrier in this kernel

    const bool mixed = (cb0 < NCL && cb0 + 127 >= NCL) || (cb0 + 127 >= TOTC);
    const int  halfsel = (cb0 >= NCL) ? 1 : 0;

    const int r0 = wm * 64 + l31;            // A rows this lane reads
    const int r1 = r0 + 32;                  // (r0&7)==(r1&7): same swizzle key
    const int swz = (r0 & 7) << 4;

    float sreg0[8], sreg1[8];

#pragma unroll
    for (int bt = 0; bt < 8; ++bt) {
        // B base for this wave: batch col bt*128 + wn*32 + l31, panel hi
        const unsigned short* bb = xnT + (size_t)hi * (BATCH * 8)
                                 + (size_t)(bt * 128 + wn * 32 + l31) * 8;

        f32x16 acc0 = (f32x16)(0.0f), acc1 = (f32x16)(0.0f);
#pragma unroll
        for (int kk = 0; kk < 16; ++kk) {
            const bf16x8 bf = *(const bf16x8*)(bb + (size_t)kk * 16384);
            const int kb = ((kk * 2 + hi) * 16) ^ swz;
            const bf16x8 a0 = *(const bf16x8*)((const char*)Ab + r0 * 512 + kb);
            const bf16x8 a1 = *(const bf16x8*)((const char*)Ab + r1 * 512 + kb);
            acc0 = __builtin_amdgcn_mfma_f32_32x32x16_bf16(a0, bf, acc0, 0, 0, 0);
            acc1 = __builtin_amdgcn_mfma_f32_32x32x16_bf16(a1, bf, acc1, 0, 0, 0);
        }

        // ---- epilogue: e = exp(20*d - 20); sum over this wave's 64 clusters
        if (!mixed) {
            float s = 0.0f;
#pragma unroll
            for (int r = 0; r < 16; ++r) {
                s += __expf(fmaf(acc0[r], 20.0f, -20.0f));
                s += __expf(fmaf(acc1[r], 20.0f, -20.0f));
            }
            s += __shfl_xor(s, 32, 64);
            sreg0[bt] = s;
            sreg1[bt] = 0.0f;
        } else {
            float sh0 = 0.0f, sh1 = 0.0f;
#pragma unroll
            for (int mt = 0; mt < 2; ++mt)
#pragma unroll
                for (int r = 0; r < 16; ++r) {
                    const int cl = cb0 + wm * 64 + mt * 32 +
                                   (r & 3) + 8 * (r >> 2) + 4 * hi;
                    const bool valid = cl < TOTC;
                    float e = __expf(fmaf((mt ? acc1[r] : acc0[r]), 20.0f, -20.0f));
                    e = valid ? e : 0.0f;
                    sh0 += (cl < NCL) ? e : 0.0f;
                    sh1 += (cl < NCL) ? 0.0f : e;
                }
            sh0 += __shfl_xor(sh0, 32, 64);
            sh1 += __shfl_xor(sh1, 32, 64);
            sreg0[bt] = sh0;
            sreg1[bt] = sh1;
        }
    }

    // ---- all atomics at the very end: fire-and-forget ----
    if (hi == 0) {
        if (!mixed) {
#pragma unroll
            for (int bt = 0; bt < 8; ++bt) {
                const int bcol = bt * 128 + wn * 32 + l31;
                atomicAdd(&Ss[bcol * 2 + halfsel], sreg0[bt]);
            }
        } else {
#pragma unroll
            for (int bt = 0; bt < 8; ++bt) {
                const int bcol = bt * 128 + wn * 32 + l31;
                atomicAdd(&Ss[bcol * 2 + 0], sreg0[bt]);
                atomicAdd(&Ss[bcol * 2 + 1], sreg1[bt]);
            }
        }
    }
}

// ---------------------------------------------------------------------------
// Kernel 3: loss = 0.5 * mean_b[(20+log S0 - z0) + (20+log S1 - z1)],
// summing the 16 slices first.
// ---------------------------------------------------------------------------
__global__ __launch_bounds__(256) void k_loss(const float* __restrict__ Sx,
                                              const float* __restrict__ z,
                                              float* __restrict__ out) {
    const int t = threadIdx.x;
    float part = 0.0f;
    for (int r = t; r < BATCH; r += 256) {
        float s0 = 0.0f, s1 = 0.0f;
#pragma unroll
        for (int sl = 0; sl < NSLICE; ++sl) {
            s0 += Sx[sl * (BATCH * 2) + r * 2 + 0];
            s1 += Sx[sl * (BATCH * 2) + r * 2 + 1];
        }
        part += 40.0f + logf(s0) + logf(s1) - z[r * 2 + 0] - z[r * 2 + 1];
    }
#pragma unroll
    for (int o = 1; o < 64; o <<= 1) part += __shfl_xor(part, o, 64);
    __shared__ float ws[4];
    if ((t & 63) == 0) ws[t >> 6] = part;
    __syncthreads();
    if (t == 0) {
        const float tot = ws[0] + ws[1] + ws[2] + ws[3];
        out[0] = 0.5f * tot / (float)BATCH;
    }
}

// ---------------------------------------------------------------------------
extern "C" void kernel_launch(void* const* d_in, const int* in_sizes, int n_in,
                              void* d_out, int out_size, void* d_ws, size_t ws_size,
                              hipStream_t stream) {
    const float* inputs  = (const float*)d_in[0];
    const int*   targets = (const int*)d_in[1];
    const float* feats   = (const float*)d_in[2];
    float* out = (float*)d_out;

    unsigned short* xnT = (unsigned short*)d_ws;          // 32 panels * 16 KB = 512 KB
    float* Sx = (float*)(xnT + BATCH * DIM);              // 16*1024*2 f32 = 128 KB
    float* zt = Sx + NSLICE * BATCH * 2;                  // 1024*2 f32

    k_prep<<<BATCH, 64, 0, stream>>>(inputs, targets, feats, xnT, Sx, zt);
    const int nblk = (TOTC + 127) / 128;                  // 782
    k_main<<<nblk, 512, 0, stream>>>(xnT, feats, Sx);
    k_loss<<<1, 256, 0, stream>>>(Sx, zt, out);
}